// Round 20
// baseline (118.627 us; speedup 1.0000x reference)
//
#include <hip/hip_runtime.h>
#include <cstdint>
#include <cstddef>

#define D_DIM   256
#define B_ROWS  1024
#define C_CLS   200000
#define S_SC    64.0f
#define LOG2E_F 1.44269504088896340736f
#define LN2_F   0.69314718055994530942f
#define COS_M_F 0.87758256189037271612f
#define SIN_M_F 0.47942553860420300027f
#define EPS_F   1e-8f

#define CT 256                     /* classes per block (M side) */
#define BT 128                     /* batch rows per block (N side) */
#define NCT 782                    /* 782*256 = 200192 class tiles */
#define CPAD (NCT * CT)            /* 200192 */
#define NPADROW (CPAD - C_CLS)     /* 192 zero rows -> exp2(0)=1 each */
#define NBLK (NCT * 8)             /* 6256 = 8*782, bijective XCD swizzle */

// A-operand MX scale = 2^6 = 64 (E8M0 byte 127+6 = 133 = 0x85): the MFMA
// emits 64*log2e*cos directly (log2e baked into pbf8), so epilogue = exp2(acc).
#define SCALE_A 0x85858585
#define SCALE_1 0x7F7F7F7F

typedef int   i32x4  __attribute__((ext_vector_type(4)));
typedef int   i32x8  __attribute__((ext_vector_type(8)));
typedef float f32x16 __attribute__((ext_vector_type(16)));

// ---- kernel 1: normalize {proto*log2e, emb} -> fp8 e4m3; zero sums/out ------
__global__ void k_norm_all8(const float* __restrict__ emb,
                            const float* __restrict__ proto,
                            unsigned char* __restrict__ ebf8,
                            unsigned char* __restrict__ pbf8,
                            float* __restrict__ sums,
                            float* __restrict__ out) {
  int wid = threadIdx.x >> 6, lane = threadIdx.x & 63;
  int idx = (blockIdx.x << 2) + wid;
  const float* src;
  unsigned char* dst;
  float post = 1.0f;
  if (idx < CPAD) {
    if (idx >= C_CLS) {
      *reinterpret_cast<unsigned int*>(pbf8 + (size_t)idx * D_DIM + lane * 4) = 0u;
      return;
    }
    src = proto + (size_t)idx * D_DIM;
    dst = pbf8 + (size_t)idx * D_DIM;
    post = LOG2E_F;                           // bake log2e into the A operand
  } else {
    int row = idx - CPAD;
    if (lane == 0) sums[row] = 0.0f;          // re-zeroed every call
    if (idx == CPAD && lane == 1) *out = 0.0f;
    src = emb + (size_t)row * D_DIM;
    dst = ebf8 + (size_t)row * D_DIM;
  }
  const float4 v = *reinterpret_cast<const float4*>(src + lane * 4);
  float ss = v.x * v.x + v.y * v.y + v.z * v.z + v.w * v.w;
#pragma unroll
  for (int m = 32; m >= 1; m >>= 1) ss += __shfl_xor(ss, m, 64);
  float inv = post / fmaxf(sqrtf(ss), 1e-12f);
  int packed = 0;
  packed = __builtin_amdgcn_cvt_pk_fp8_f32(v.x * inv, v.y * inv, packed, false);
  packed = __builtin_amdgcn_cvt_pk_fp8_f32(v.z * inv, v.w * inv, packed, true);
  *reinterpret_cast<int*>(dst + lane * 4) = packed;
}

// ---------------- kernel 2: swapped MX-fp8 GEMM + in-lane exp2-sum ------------
// R19 body (best measured: 116.4 us) with two register-shape-neutral deltas:
// (1) 4 independent exp2 partial sums (breaks the 64-long serial add chain),
// (2) per-wc bsum rows -> plain LDS stores instead of 128 LDS atomics/block.
__global__ __launch_bounds__(512, 4) void k_gemm_sw(
    const unsigned char* __restrict__ ebf8, const unsigned char* __restrict__ pbf8,
    float* __restrict__ sums) {
  __shared__ __align__(16) unsigned char Pls[CT * 256];   // 64 KiB, row = 256 B
  __shared__ float bsum[2][BT];                           // per-wc rows, 1 KiB

  const int t = threadIdx.x;
  const int lane = t & 63;
  const int rsel = lane & 31;       // row (A) / col (B) within 32
  const int h = lane >> 5;          // k-half of the 64-K window
  const int wv = t >> 6;
  const int wc = wv >> 2;           // 0..1 : 128-class strip
  const int wb = wv & 3;            // 0..3 : 32-batch strip

  int bid = (int)blockIdx.x;
  int w = (bid & 7) * NCT + (bid >> 3);   // bijective: NBLK = 8*NCT
  const int ct = w >> 3;                  // c-tiles contiguous per XCD
  const int bt = w & 7;
  const int c0 = ct * CT;
  const int b0 = bt * BT;

  // ---- prologue: stage whole proto tile (256 rows x 256 B), XOR ^(r&15) ----
#pragma unroll
  for (int j = 0; j < 8; ++j) {
    int G = j * 512 + t;            // 16-B granule index, 0..4095
    int r = G >> 4, p = G & 15;
    int lg = p ^ (r & 15);
    const unsigned char* g = pbf8 + (size_t)(c0 + r) * D_DIM + lg * 16;
    __builtin_amdgcn_global_load_lds(
        (const __attribute__((address_space(1))) unsigned int*)(const void*)g,
        (__attribute__((address_space(3))) unsigned int*)(void*)(Pls + G * 16),
        16, 0, 0);
  }

  f32x16 acc[4];
#pragma unroll
  for (int mi = 0; mi < 4; ++mi)
#pragma unroll
    for (int e = 0; e < 16; ++e) acc[mi][e] = 0.0f;

  asm volatile("s_waitcnt vmcnt(0)" ::: "memory");
  __syncthreads();                   // ONLY barrier before the epilogue

  // ---- barrier-free K-loop: 4 steps of K=64 ----
  const unsigned char* ebase =
      ebf8 + (size_t)(b0 + wb * 32 + rsel) * D_DIM + h * 32;
#pragma unroll
  for (int ks = 0; ks < 4; ++ks) {
    i32x4 blo = *reinterpret_cast<const i32x4*>(ebase + ks * 64);
    i32x4 bhi = *reinterpret_cast<const i32x4*>(ebase + ks * 64 + 16);
    i32x8 bf = __builtin_shufflevector(blo, bhi, 0, 1, 2, 3, 4, 5, 6, 7);
    const int g = ks * 4 + h * 2;
#pragma unroll
    for (int mi = 0; mi < 4; ++mi) {
      int r = wc * 128 + mi * 32 + rsel;
      int p0 = g ^ (r & 15), p1 = (g + 1) ^ (r & 15);
      i32x4 lo = *reinterpret_cast<const i32x4*>(Pls + r * 256 + p0 * 16);
      i32x4 hi = *reinterpret_cast<const i32x4*>(Pls + r * 256 + p1 * 16);
      i32x8 af = __builtin_shufflevector(lo, hi, 0, 1, 2, 3, 4, 5, 6, 7);
      acc[mi] = __builtin_amdgcn_mfma_scale_f32_32x32x64_f8f6f4(
          af, bf, acc[mi], 0, 0,            // cbsz=fp8, blgp=fp8
          0, SCALE_A, 0, SCALE_1);          // A-scale=2^6, B-scale=1
    }
  }

  // ---- epilogue: in-lane exp2-sum, 4 independent partial chains ----
  float bp0 = 0.0f, bp1 = 0.0f, bp2 = 0.0f, bp3 = 0.0f;
#pragma unroll
  for (int reg = 0; reg < 16; ++reg) {
    bp0 += __builtin_amdgcn_exp2f(acc[0][reg]);
    bp1 += __builtin_amdgcn_exp2f(acc[1][reg]);
    bp2 += __builtin_amdgcn_exp2f(acc[2][reg]);
    bp3 += __builtin_amdgcn_exp2f(acc[3][reg]);
  }
  float bp = (bp0 + bp1) + (bp2 + bp3);
  bp += __shfl_xor(bp, 32, 64);      // combine the two k-half lane groups
  if (lane < 32) bsum[wc][wb * 32 + rsel] = bp;   // unique writer per address
  __syncthreads();
  if (t < BT) atomicAdd(&sums[b0 + t], bsum[0][t] + bsum[1][t]);
}

// ---------------- kernel 3: label column + final loss -------------------------
__device__ __forceinline__ float f8tof(unsigned char u) {
  int e = (u >> 3) & 15, m = u & 7;
  float mag = e ? ldexpf((float)(8 + m), e - 10) : ldexpf((float)m, -9);
  return (u & 0x80) ? -mag : mag;
}

__global__ void k_finalize(const unsigned char* __restrict__ ebf8,
                           const unsigned char* __restrict__ pbf8,
                           const int* __restrict__ labels,
                           const float* __restrict__ sums,
                           float* __restrict__ out) {
  __shared__ float part[4];
  int wid = threadIdx.x >> 6, lane = threadIdx.x & 63;
  int b = (blockIdx.x << 2) + wid;
  int lab = labels[b];
  const unsigned char* e = ebf8 + (size_t)b * D_DIM + lane * 4;
  const unsigned char* p = pbf8 + (size_t)lab * D_DIM + lane * 4;
  unsigned int eu = *reinterpret_cast<const unsigned int*>(e);
  unsigned int pu = *reinterpret_cast<const unsigned int*>(p);
  float dot_s = 0.0f;                 // = log2e * cos_q (pbf8 is log2e-scaled)
#pragma unroll
  for (int i = 0; i < 4; ++i)
    dot_s += f8tof((eu >> (8 * i)) & 0xff) * f8tof((pu >> (8 * i)) & 0xff);
#pragma unroll
  for (int m = 32; m >= 1; m >>= 1) dot_s += __shfl_xor(dot_s, m, 64);
  if (lane == 0) {
    float cs = dot_s * LN2_F;         // undo the log2e bake
    float sn = sqrtf(fmaxf(1.0f - cs * cs, EPS_F));
    sn = fminf(fmaxf(sn, EPS_F), 1.0f - EPS_F);
    float phi = cs * COS_M_F - sn * SIN_M_F;
    float sp = S_SC * phi;
    // label term as the GEMM folded it into sums: exp2(64 * dot_s)
    float el = __builtin_amdgcn_exp2f(S_SC * dot_s);
    float total = sums[b] - (float)NPADROW - el + __expf(sp);
    part[wid] = logf(total) - sp;
  }
  __syncthreads();
  if (threadIdx.x == 0) {
    float s = part[0] + part[1] + part[2] + part[3];
    atomicAdd(out, s * (1.0f / (float)B_ROWS));
  }
}

// ---------------- launcher ----------------------------------------------------
extern "C" void kernel_launch(void* const* d_in, const int* in_sizes, int n_in,
                              void* d_out, int out_size, void* d_ws, size_t ws_size,
                              hipStream_t stream) {
  const float* emb    = (const float*)d_in[0];
  const int*   labels = (const int*)d_in[1];
  const float* proto  = (const float*)d_in[2];
  float* out = (float*)d_out;

  char* ws = (char*)d_ws;
  unsigned char* ebf8 = (unsigned char*)ws;                 // 262144 B
  float* sums = (float*)(ws + 262144);                      // 4096 B
  unsigned char* pbf8 = (unsigned char*)(ws + 2097152);     // CPAD*256 = 51.2 MB

  k_norm_all8<<<(CPAD + B_ROWS) / 4, 256, 0, stream>>>(emb, proto, ebf8, pbf8,
                                                       sums, out);
  k_gemm_sw<<<NBLK, 512, 0, stream>>>(ebf8, pbf8, sums);
  k_finalize<<<B_ROWS / 4, 256, 0, stream>>>(ebf8, pbf8, labels, sums, out);
}

// Round 21
// 115.870 us; speedup vs baseline: 1.0238x; 1.0238x over previous
//
#include <hip/hip_runtime.h>
#include <cstdint>
#include <cstddef>

#define D_DIM   256
#define B_ROWS  1024
#define C_CLS   200000
#define S_SC    64.0f
#define LOG2E_F 1.44269504088896340736f
#define LN2_F   0.69314718055994530942f
#define COS_M_F 0.87758256189037271612f
#define SIN_M_F 0.47942553860420300027f
#define EPS_F   1e-8f

#define CT 256                     /* classes per block (M side) */
#define BT 128                     /* batch rows per block (N side) */
#define NCT 782                    /* 782*256 = 200192 class tiles */
#define CPAD (NCT * CT)            /* 200192 */
#define NPADROW (CPAD - C_CLS)     /* 192 zero rows -> exp2(0)=1 each */
#define NBLK (NCT * 8)             /* 6256 = 8*782, bijective XCD swizzle */

// A-operand MX scale = 2^6 = 64 (E8M0 byte 127+6 = 133 = 0x85): the MFMA
// emits 64*log2e*cos directly (log2e baked into pbf8), so epilogue = exp2(acc).
#define SCALE_A 0x85858585
#define SCALE_1 0x7F7F7F7F

typedef int   i32x4  __attribute__((ext_vector_type(4)));
typedef int   i32x8  __attribute__((ext_vector_type(8)));
typedef float f32x16 __attribute__((ext_vector_type(16)));

// ---- kernel 1: normalize {proto*log2e, emb} -> fp8 e4m3; zero sums/out ------
__global__ void k_norm_all8(const float* __restrict__ emb,
                            const float* __restrict__ proto,
                            unsigned char* __restrict__ ebf8,
                            unsigned char* __restrict__ pbf8,
                            float* __restrict__ sums,
                            float* __restrict__ out) {
  int wid = threadIdx.x >> 6, lane = threadIdx.x & 63;
  int idx = (blockIdx.x << 2) + wid;
  const float* src;
  unsigned char* dst;
  float post = 1.0f;
  if (idx < CPAD) {
    if (idx >= C_CLS) {
      *reinterpret_cast<unsigned int*>(pbf8 + (size_t)idx * D_DIM + lane * 4) = 0u;
      return;
    }
    src = proto + (size_t)idx * D_DIM;
    dst = pbf8 + (size_t)idx * D_DIM;
    post = LOG2E_F;                           // bake log2e into the A operand
  } else {
    int row = idx - CPAD;
    if (lane == 0) sums[row] = 0.0f;          // re-zeroed every call
    if (idx == CPAD && lane == 1) *out = 0.0f;
    src = emb + (size_t)row * D_DIM;
    dst = ebf8 + (size_t)row * D_DIM;
  }
  const float4 v = *reinterpret_cast<const float4*>(src + lane * 4);
  float ss = v.x * v.x + v.y * v.y + v.z * v.z + v.w * v.w;
#pragma unroll
  for (int m = 32; m >= 1; m >>= 1) ss += __shfl_xor(ss, m, 64);
  float inv = post / fmaxf(sqrtf(ss), 1e-12f);
  int packed = 0;
  packed = __builtin_amdgcn_cvt_pk_fp8_f32(v.x * inv, v.y * inv, packed, false);
  packed = __builtin_amdgcn_cvt_pk_fp8_f32(v.z * inv, v.w * inv, packed, true);
  *reinterpret_cast<int*>(dst + lane * 4) = packed;
}

// ---------------- kernel 2: swapped MX-fp8 GEMM + in-lane exp2-sum ------------
// R19 verbatim -- session best (116.4 us total). D[c,b] = mfma(protoFrag,
// embFrag): class dim lane-local => sum_c exp2() needs no per-element
// shuffles. Proto tile (64 KB, all K) staged once -> barrier-free K-loop.
// A-scale=2^6 + log2e-baked pbf8 => epilogue is a bare exp2(acc).
__global__ __launch_bounds__(512, 4) void k_gemm_sw(
    const unsigned char* __restrict__ ebf8, const unsigned char* __restrict__ pbf8,
    float* __restrict__ sums) {
  __shared__ __align__(16) unsigned char Pls[CT * 256];   // 64 KiB, row = 256 B
  __shared__ float bsum[BT];

  const int t = threadIdx.x;
  const int lane = t & 63;
  const int rsel = lane & 31;       // row (A) / col (B) within 32
  const int h = lane >> 5;          // k-half of the 64-K window
  const int wv = t >> 6;
  const int wc = wv >> 2;           // 0..1 : 128-class strip
  const int wb = wv & 3;            // 0..3 : 32-batch strip

  int bid = (int)blockIdx.x;
  int w = (bid & 7) * NCT + (bid >> 3);   // bijective: NBLK = 8*NCT
  const int ct = w >> 3;                  // c-tiles contiguous per XCD
  const int bt = w & 7;
  const int c0 = ct * CT;
  const int b0 = bt * BT;

  // ---- prologue: stage whole proto tile (256 rows x 256 B), XOR ^(r&15) ----
#pragma unroll
  for (int j = 0; j < 8; ++j) {
    int G = j * 512 + t;            // 16-B granule index, 0..4095
    int r = G >> 4, p = G & 15;
    int lg = p ^ (r & 15);
    const unsigned char* g = pbf8 + (size_t)(c0 + r) * D_DIM + lg * 16;
    __builtin_amdgcn_global_load_lds(
        (const __attribute__((address_space(1))) unsigned int*)(const void*)g,
        (__attribute__((address_space(3))) unsigned int*)(void*)(Pls + G * 16),
        16, 0, 0);
  }
  if (t < BT) bsum[t] = 0.0f;

  f32x16 acc[4];
#pragma unroll
  for (int mi = 0; mi < 4; ++mi)
#pragma unroll
    for (int e = 0; e < 16; ++e) acc[mi][e] = 0.0f;

  asm volatile("s_waitcnt vmcnt(0)" ::: "memory");
  __syncthreads();                   // ONLY barrier before the epilogue

  // ---- barrier-free K-loop: 4 steps of K=64 ----
  const unsigned char* ebase =
      ebf8 + (size_t)(b0 + wb * 32 + rsel) * D_DIM + h * 32;
#pragma unroll
  for (int ks = 0; ks < 4; ++ks) {
    i32x4 blo = *reinterpret_cast<const i32x4*>(ebase + ks * 64);
    i32x4 bhi = *reinterpret_cast<const i32x4*>(ebase + ks * 64 + 16);
    i32x8 bf = __builtin_shufflevector(blo, bhi, 0, 1, 2, 3, 4, 5, 6, 7);
    const int g = ks * 4 + h * 2;
#pragma unroll
    for (int mi = 0; mi < 4; ++mi) {
      int r = wc * 128 + mi * 32 + rsel;
      int p0 = g ^ (r & 15), p1 = (g + 1) ^ (r & 15);
      i32x4 lo = *reinterpret_cast<const i32x4*>(Pls + r * 256 + p0 * 16);
      i32x4 hi = *reinterpret_cast<const i32x4*>(Pls + r * 256 + p1 * 16);
      i32x8 af = __builtin_shufflevector(lo, hi, 0, 1, 2, 3, 4, 5, 6, 7);
      acc[mi] = __builtin_amdgcn_mfma_scale_f32_32x32x64_f8f6f4(
          af, bf, acc[mi], 0, 0,            // cbsz=fp8, blgp=fp8
          0, SCALE_A, 0, SCALE_1);          // A-scale=2^6, B-scale=1
    }
  }

  // ---- epilogue: in-lane exp2-sum over all 64 class rows this lane holds ----
  float bp = 0.0f;
#pragma unroll
  for (int mi = 0; mi < 4; ++mi)
#pragma unroll
    for (int reg = 0; reg < 16; ++reg)
      bp += __builtin_amdgcn_exp2f(acc[mi][reg]);
  bp += __shfl_xor(bp, 32, 64);      // combine the two k-half lane groups
  if (lane < 32) atomicAdd(&bsum[wb * 32 + rsel], bp);
  __syncthreads();
  if (t < BT) atomicAdd(&sums[b0 + t], bsum[t]);
}

// ---------------- kernel 3: label column + final loss -------------------------
__device__ __forceinline__ float f8tof(unsigned char u) {
  int e = (u >> 3) & 15, m = u & 7;
  float mag = e ? ldexpf((float)(8 + m), e - 10) : ldexpf((float)m, -9);
  return (u & 0x80) ? -mag : mag;
}

__global__ void k_finalize(const unsigned char* __restrict__ ebf8,
                           const unsigned char* __restrict__ pbf8,
                           const int* __restrict__ labels,
                           const float* __restrict__ sums,
                           float* __restrict__ out) {
  __shared__ float part[4];
  int wid = threadIdx.x >> 6, lane = threadIdx.x & 63;
  int b = (blockIdx.x << 2) + wid;
  int lab = labels[b];
  const unsigned char* e = ebf8 + (size_t)b * D_DIM + lane * 4;
  const unsigned char* p = pbf8 + (size_t)lab * D_DIM + lane * 4;
  unsigned int eu = *reinterpret_cast<const unsigned int*>(e);
  unsigned int pu = *reinterpret_cast<const unsigned int*>(p);
  float dot_s = 0.0f;                 // = log2e * cos_q (pbf8 is log2e-scaled)
#pragma unroll
  for (int i = 0; i < 4; ++i)
    dot_s += f8tof((eu >> (8 * i)) & 0xff) * f8tof((pu >> (8 * i)) & 0xff);
#pragma unroll
  for (int m = 32; m >= 1; m >>= 1) dot_s += __shfl_xor(dot_s, m, 64);
  if (lane == 0) {
    float cs = dot_s * LN2_F;         // undo the log2e bake
    float sn = sqrtf(fmaxf(1.0f - cs * cs, EPS_F));
    sn = fminf(fmaxf(sn, EPS_F), 1.0f - EPS_F);
    float phi = cs * COS_M_F - sn * SIN_M_F;
    float sp = S_SC * phi;
    // label term as the GEMM folded it into sums: exp2(64 * dot_s)
    float el = __builtin_amdgcn_exp2f(S_SC * dot_s);
    float total = sums[b] - (float)NPADROW - el + __expf(sp);
    part[wid] = logf(total) - sp;
  }
  __syncthreads();
  if (threadIdx.x == 0) {
    float s = part[0] + part[1] + part[2] + part[3];
    atomicAdd(out, s * (1.0f / (float)B_ROWS));
  }
}

// ---------------- launcher ----------------------------------------------------
extern "C" void kernel_launch(void* const* d_in, const int* in_sizes, int n_in,
                              void* d_out, int out_size, void* d_ws, size_t ws_size,
                              hipStream_t stream) {
  const float* emb    = (const float*)d_in[0];
  const int*   labels = (const int*)d_in[1];
  const float* proto  = (const float*)d_in[2];
  float* out = (float*)d_out;

  char* ws = (char*)d_ws;
  unsigned char* ebf8 = (unsigned char*)ws;                 // 262144 B
  float* sums = (float*)(ws + 262144);                      // 4096 B
  unsigned char* pbf8 = (unsigned char*)(ws + 2097152);     // CPAD*256 = 51.2 MB

  k_norm_all8<<<(CPAD + B_ROWS) / 4, 256, 0, stream>>>(emb, proto, ebf8, pbf8,
                                                       sums, out);
  k_gemm_sw<<<NBLK, 512, 0, stream>>>(ebf8, pbf8, sums);
  k_finalize<<<B_ROWS / 4, 256, 0, stream>>>(ebf8, pbf8, labels, sums, out);
}